// Round 1
// baseline (331.184 us; speedup 1.0000x reference)
//
#include <hip/hip_runtime.h>
#include <hip/hip_bf16.h>
#include <stdint.h>

// ---------- types ----------
typedef __bf16  bf16x8 __attribute__((ext_vector_type(8)));
typedef short   s16x8  __attribute__((ext_vector_type(8)));
typedef int     i32x4  __attribute__((ext_vector_type(4)));
typedef float   f32x4  __attribute__((ext_vector_type(4)));

union Frag { s16x8 s; bf16x8 b; i32x4 i; };

static __device__ __forceinline__ short f2bf(float f) {
    union { float f; unsigned u; } v; v.f = f;
    unsigned r = (v.u + 0x7FFFu + ((v.u >> 16) & 1u)) >> 16;   // RNE
    return (short)r;
}
static __device__ __forceinline__ float bf2f(short s) {
    union { unsigned u; float f; } v; v.u = ((unsigned)(unsigned short)s) << 16;
    return v.f;
}
static __device__ __forceinline__ float fast_rcp(float x) { return __builtin_amdgcn_rcpf(x); }
static __device__ __forceinline__ float sigm(float x) { return fast_rcp(1.0f + __expf(-x)); }
static __device__ __forceinline__ float tanh_fast(float x) {
    float e = __expf(-2.0f * x);
    return (1.0f - e) * fast_rcp(1.0f + e);
}
static __device__ __forceinline__ f32x4 mfma16(bf16x8 a, bf16x8 b, f32x4 c) {
    return __builtin_amdgcn_mfma_f32_16x16x32_bf16(a, b, c, 0, 0, 0);
}

// Constants
#define TT 128
#define BB 2048
#define HH 64
#define FF 128
#define AA 15
#define NROWS (TT*BB)        // 262144
#define NTILES (NROWS/16)    // 16384 row-tiles of 16
#define LOGITS_OFF 0
#define VF_OFF   3932160
#define HT_OFF   4194304
#define CT_OFF   4325376

// y_sw / z_sw swizzled layout: per 16-row tile rt: 1024 bf16 = [kf(2)][lane(64)][8],
// lane l holds rows m=l&15, k = 32*kf + 8*(l>>4) + j  (A-fragment order).

// ============================ encoder ============================
// y = tanh(tanh(x@W1+b1)@W2+b2), written bf16 swizzled.
__global__ __launch_bounds__(256) void enc_kernel(
    const float* __restrict__ x, const float* __restrict__ W1, const float* __restrict__ b1,
    const float* __restrict__ W2, const float* __restrict__ b2, short* __restrict__ y_sw)
{
    __shared__ short w1t[64][136];       // [n][k]  (W1 transposed, bf16)
    __shared__ short w2t[64][72];
    __shared__ short c1buf[4][16][72];   // per-wave layer1 output tile [row][k]
    __shared__ short ybuf[4][16][72];

    const int tid  = threadIdx.x;
    const int lane = tid & 63;
    const int w    = tid >> 6;
    const int c    = lane & 15;
    const int q    = lane >> 4;

    for (int i = tid; i < 128*64; i += 256) { int k = i >> 6, n = i & 63; w1t[n][k] = f2bf(W1[i]); }
    for (int i = tid; i < 64*64;  i += 256) { int k = i >> 6, n = i & 63; w2t[n][k] = f2bf(W2[i]); }

    float b1v[4], b2v[4];
#pragma unroll
    for (int ct = 0; ct < 4; ++ct) { b1v[ct] = b1[16*ct + c]; b2v[ct] = b2[16*ct + c]; }
    __syncthreads();

    for (int it = 0; it < 4; ++it) {
        const int wt = it*4096 + blockIdx.x*4 + w;
        const int r0 = wt * 16;
        // ---- layer 1: A-frags straight from global x (fp32 -> bf16)
        Frag af[4];
#pragma unroll
        for (int kf = 0; kf < 4; ++kf) {
            const float* xp = x + (size_t)(r0 + c)*FF + 32*kf + 8*q;
            f32x4 x0 = *(const f32x4*)xp;
            f32x4 x1 = *(const f32x4*)(xp + 4);
#pragma unroll
            for (int jj = 0; jj < 4; ++jj) { af[kf].s[jj] = f2bf(x0[jj]); af[kf].s[4+jj] = f2bf(x1[jj]); }
        }
        f32x4 acc[4];
#pragma unroll
        for (int ct = 0; ct < 4; ++ct) acc[ct] = (f32x4){b1v[ct], b1v[ct], b1v[ct], b1v[ct]};
#pragma unroll
        for (int kf = 0; kf < 4; ++kf)
#pragma unroll
            for (int ct = 0; ct < 4; ++ct) {
                Frag bf; bf.s = *(const s16x8*)&w1t[16*ct + c][32*kf + 8*q];
                acc[ct] = mfma16(af[kf].b, bf.b, acc[ct]);
            }
#pragma unroll
        for (int ct = 0; ct < 4; ++ct)
#pragma unroll
            for (int i = 0; i < 4; ++i)
                c1buf[w][4*q + i][16*ct + c] = f2bf(tanh_fast(acc[ct][i]));
        // ---- layer 2 (same-wave producer/consumer; compiler inserts lgkmcnt)
        Frag a2[2];
#pragma unroll
        for (int kf = 0; kf < 2; ++kf) a2[kf].s = *(const s16x8*)&c1buf[w][c][32*kf + 8*q];
        f32x4 acc2[4];
#pragma unroll
        for (int ct = 0; ct < 4; ++ct) acc2[ct] = (f32x4){b2v[ct], b2v[ct], b2v[ct], b2v[ct]};
#pragma unroll
        for (int kf = 0; kf < 2; ++kf)
#pragma unroll
            for (int ct = 0; ct < 4; ++ct) {
                Frag bf; bf.s = *(const s16x8*)&w2t[16*ct + c][32*kf + 8*q];
                acc2[ct] = mfma16(a2[kf].b, bf.b, acc2[ct]);
            }
#pragma unroll
        for (int ct = 0; ct < 4; ++ct)
#pragma unroll
            for (int i = 0; i < 4; ++i)
                ybuf[w][4*q + i][16*ct + c] = f2bf(tanh_fast(acc2[ct][i]));
        // swizzled store (read back in A-frag order)
#pragma unroll
        for (int kf = 0; kf < 2; ++kf) {
            s16x8 yv = *(const s16x8*)&ybuf[w][c][32*kf + 8*q];
            *(s16x8*)(y_sw + (size_t)wt*1024 + kf*512 + lane*8) = yv;
        }
    }
}

// ============================ LSTM scan ============================
// 128 blocks x 256 thr. Block owns 16 batch rows. Wave w owns hidden cols
// j in [16w,16w+16) for all 4 gates (G-tiles {w, w+4, w+8, w+12}).
__global__ __launch_bounds__(256, 1) void scan_kernel(
    const short* __restrict__ y_sw, const float* __restrict__ done,
    const float* __restrict__ h0, const float* __restrict__ c0,
    const float* __restrict__ Wih, const float* __restrict__ bih,
    const float* __restrict__ Whh, const float* __restrict__ bhh,
    short* __restrict__ z_sw, float* __restrict__ hT_out, float* __restrict__ cT_out)
{
    __shared__ short hbuf[2][16][72];    // double-buffered h (bf16), [row][j]

    const int tid  = threadIdx.x;
    const int lane = tid & 63;
    const int w    = tid >> 6;
    const int c    = lane & 15;
    const int q    = lane >> 4;
    const int blk  = blockIdx.x;
    const int b0   = blk * 16;
    const int jcol = 16*w + c;

    // weight B-fragments: Wcomb[k][col], k<64 from Wih (y part), k>=64 from Whh (h part)
    Frag  wf[4][4];
    float biasv[4];
#pragma unroll
    for (int a = 0; a < 4; ++a) {
        const int col = 64*a + jcol;
        biasv[a] = bih[col] + bhh[col];
#pragma unroll
        for (int kf = 0; kf < 4; ++kf) {
            const float* wp = (kf < 2) ? (Wih + (size_t)col*HH + 32*kf + 8*q)
                                       : (Whh + (size_t)col*HH + 32*(kf-2) + 8*q);
            f32x4 w0 = *(const f32x4*)wp;
            f32x4 w1 = *(const f32x4*)(wp + 4);
#pragma unroll
            for (int jj = 0; jj < 4; ++jj) { wf[a][kf].s[jj] = f2bf(w0[jj]); wf[a][kf].s[4+jj] = f2bf(w1[jj]); }
        }
    }
    // c state (fp32, registers): rows 4q+i, col jcol
    float cst[4];
#pragma unroll
    for (int i = 0; i < 4; ++i) cst[i] = c0[(size_t)(b0 + 4*q + i)*HH + jcol];
    // h0 -> hbuf[0]
    {
        int mm = tid & 15, j4 = tid >> 4;
        f32x4 hv = *(const f32x4*)(h0 + (size_t)(b0 + mm)*HH + 4*j4);
#pragma unroll
        for (int ii = 0; ii < 4; ++ii) hbuf[0][mm][4*j4 + ii] = f2bf(hv[ii]);
    }
    // prefetch t=0
    Frag yc0, yc1;
    yc0.s = *(const s16x8*)(y_sw + (size_t)blk*1024 + lane*8);
    yc1.s = *(const s16x8*)(y_sw + (size_t)blk*1024 + 512 + lane*8);
    float dmv = done[b0 + c];
    f32x4 dcv = *(const f32x4*)(done + b0 + 4*q);
    __syncthreads();

    for (int t = 0; t < TT; ++t) {
        const int cur = t & 1, nxt = cur ^ 1;
        // h_{t-1} A-fragments
        Frag hf0, hf1;
        hf0.s = *(const s16x8*)&hbuf[cur][c][8*q];
        hf1.s = *(const s16x8*)&hbuf[cur][c][32 + 8*q];
        if (t > 0) {   // stream z_{t-1} (unmasked h) to workspace
            short* zp = z_sw + ((size_t)(t-1)*128 + blk)*1024 + lane*8;
            *(s16x8*)zp         = hf0.s;
            *(s16x8*)(zp + 512) = hf1.s;
        }
        // done-mask h (done is exactly 0.0 or 1.0 -> bitwise select)
        const int msk = (dmv != 0.0f) ? 0 : -1;
        Frag h0m, h1m;
#pragma unroll
        for (int k = 0; k < 4; ++k) { h0m.i[k] = hf0.i[k] & msk; h1m.i[k] = hf1.i[k] & msk; }
        // prefetch t+1 (latency hidden under MFMA + elementwise)
        const int tn = (t < TT-1) ? t + 1 : TT-1;
        Frag yn0, yn1;
        yn0.s = *(const s16x8*)(y_sw + ((size_t)tn*128 + blk)*1024 + lane*8);
        yn1.s = *(const s16x8*)(y_sw + ((size_t)tn*128 + blk)*1024 + 512 + lane*8);
        float dmn = done[tn*BB + b0 + c];
        f32x4 dcn = *(const f32x4*)(done + tn*BB + b0 + 4*q);
        // gates: acc[a] = G[rows 4q+i][64a + jcol]
        f32x4 acc[4];
#pragma unroll
        for (int a = 0; a < 4; ++a) {
            acc[a] = (f32x4){biasv[a], biasv[a], biasv[a], biasv[a]};
            acc[a] = mfma16(yc0.b, wf[a][0].b, acc[a]);
            acc[a] = mfma16(yc1.b, wf[a][1].b, acc[a]);
            acc[a] = mfma16(h0m.b, wf[a][2].b, acc[a]);
            acc[a] = mfma16(h1m.b, wf[a][3].b, acc[a]);
        }
        // elementwise LSTM cell (fp32 c state)
#pragma unroll
        for (int i = 0; i < 4; ++i) {
            float gi = acc[0][i], gf = acc[1][i], gg = acc[2][i], go = acc[3][i];
            float cm = (dcv[i] != 0.0f) ? 0.0f : cst[i];
            float cn = sigm(gf)*cm + sigm(gi)*tanh_fast(gg);
            cst[i] = cn;
            hbuf[nxt][4*q + i][jcol] = f2bf(sigm(go)*tanh_fast(cn));
        }
        yc0 = yn0; yc1 = yn1; dmv = dmn; dcv = dcn;
        __syncthreads();   // single barrier/step (double-buffered h)
    }
    // epilogue: z_127, hT, cT
    {
        Frag hf0, hf1;
        hf0.s = *(const s16x8*)&hbuf[0][c][8*q];
        hf1.s = *(const s16x8*)&hbuf[0][c][32 + 8*q];
        short* zp = z_sw + ((size_t)(TT-1)*128 + blk)*1024 + lane*8;
        *(s16x8*)zp         = hf0.s;
        *(s16x8*)(zp + 512) = hf1.s;
    }
    {
        int mm = tid & 15, j4 = tid >> 4;
        f32x4 hv;
#pragma unroll
        for (int ii = 0; ii < 4; ++ii) hv[ii] = bf2f(hbuf[0][mm][4*j4 + ii]);
        *(f32x4*)(hT_out + (size_t)(b0 + mm)*HH + 4*j4) = hv;
    }
#pragma unroll
    for (int i = 0; i < 4; ++i) cT_out[(size_t)(b0 + 4*q + i)*HH + jcol] = cst[i];
}

// ============================ heads ============================
// [T*B,64] @ [64,16] (cols 0..14 = Wa, col 15 = Wc) -> logits + vf (fp32)
__global__ __launch_bounds__(256) void heads_kernel(
    const short* __restrict__ z_sw, const float* __restrict__ Wa, const float* __restrict__ ba,
    const float* __restrict__ Wc, const float* __restrict__ bc, float* __restrict__ out)
{
    const int tid  = threadIdx.x;
    const int lane = tid & 63;
    const int w    = tid >> 6;
    const int n    = lane & 15;
    const int q    = lane >> 4;

    Frag wf[2];
#pragma unroll
    for (int kf = 0; kf < 2; ++kf)
#pragma unroll
        for (int jj = 0; jj < 8; ++jj) {
            int k = 32*kf + 8*q + jj;
            float v = (n < 15) ? Wa[k*AA + n] : Wc[k];
            wf[kf].s[jj] = f2bf(v);
        }
    const float bv = (n < 15) ? ba[n] : bc[0];

    for (int s = 0; s < 16; ++s) {
        const int wt = s*1024 + blockIdx.x*4 + w;
        Frag a0, a1;
        a0.s = *(const s16x8*)(z_sw + (size_t)wt*1024 + lane*8);
        a1.s = *(const s16x8*)(z_sw + (size_t)wt*1024 + 512 + lane*8);
        f32x4 acc = (f32x4){bv, bv, bv, bv};
        acc = mfma16(a0.b, wf[0].b, acc);
        acc = mfma16(a1.b, wf[1].b, acc);
        const int r0 = wt*16 + 4*q;
#pragma unroll
        for (int i = 0; i < 4; ++i) {
            const int row = r0 + i;
            if (n < 15) out[LOGITS_OFF + (size_t)row*AA + n] = acc[i];
            else        out[VF_OFF + row] = acc[i];
        }
    }
}

// ============================ launch ============================
extern "C" void kernel_launch(void* const* d_in, const int* in_sizes, int n_in,
                              void* d_out, int out_size, void* d_ws, size_t ws_size,
                              hipStream_t stream) {
    const float* x    = (const float*)d_in[0];
    const float* done = (const float*)d_in[1];
    const float* h0   = (const float*)d_in[2];
    const float* c0   = (const float*)d_in[3];
    const float* W1   = (const float*)d_in[4];
    const float* b1   = (const float*)d_in[5];
    const float* W2   = (const float*)d_in[6];
    const float* b2   = (const float*)d_in[7];
    const float* Wih  = (const float*)d_in[8];
    const float* bih  = (const float*)d_in[9];
    const float* Whh  = (const float*)d_in[10];
    const float* bhh  = (const float*)d_in[11];
    const float* Wa   = (const float*)d_in[12];
    const float* ba   = (const float*)d_in[13];
    const float* Wc   = (const float*)d_in[14];
    const float* bc   = (const float*)d_in[15];
    float* out = (float*)d_out;

    short* ws   = (short*)d_ws;
    short* y_sw = ws;               // 16,777,216 bf16 = 32 MiB
    short* z_sw = ws + 16777216;    // 16,777,216 bf16 = 32 MiB

    enc_kernel<<<1024, 256, 0, stream>>>(x, W1, b1, W2, b2, y_sw);
    scan_kernel<<<128, 256, 0, stream>>>(y_sw, done, h0, c0, Wih, bih, Whh, bhh,
                                         z_sw, out + HT_OFF, out + CT_OFF);
    heads_kernel<<<256, 256, 0, stream>>>(z_sw, Wa, ba, Wc, bc, out);
}

// Round 2
// 330.718 us; speedup vs baseline: 1.0014x; 1.0014x over previous
//
#include <hip/hip_runtime.h>
#include <hip/hip_bf16.h>
#include <stdint.h>

// ---------- types ----------
typedef __bf16  bf16x8 __attribute__((ext_vector_type(8)));
typedef short   s16x8  __attribute__((ext_vector_type(8)));
typedef int     i32x4  __attribute__((ext_vector_type(4)));
typedef float   f32x4  __attribute__((ext_vector_type(4)));

union Frag { s16x8 s; bf16x8 b; i32x4 i; };

static __device__ __forceinline__ short f2bf(float f) {
    union { float f; unsigned u; } v; v.f = f;
    unsigned r = (v.u + 0x7FFFu + ((v.u >> 16) & 1u)) >> 16;   // RNE
    return (short)r;
}
static __device__ __forceinline__ float bf2f(short s) {
    union { unsigned u; float f; } v; v.u = ((unsigned)(unsigned short)s) << 16;
    return v.f;
}
static __device__ __forceinline__ float fast_rcp(float x) { return __builtin_amdgcn_rcpf(x); }
static __device__ __forceinline__ float sigm(float x) { return fast_rcp(1.0f + __expf(-x)); }
static __device__ __forceinline__ float tanh_fast(float x) {
    float e = __expf(-2.0f * x);
    return (1.0f - e) * fast_rcp(1.0f + e);
}
static __device__ __forceinline__ f32x4 mfma16(bf16x8 a, bf16x8 b, f32x4 c) {
    return __builtin_amdgcn_mfma_f32_16x16x32_bf16(a, b, c, 0, 0, 0);
}

#define GLDS(gp, lp) __builtin_amdgcn_global_load_lds( \
    (const __attribute__((address_space(1))) void*)(gp), \
    (__attribute__((address_space(3))) void*)(lp), 16, 0, 0)

// Constants
#define TT 128
#define BB 2048
#define HH 64
#define FF 128
#define AA 15
#define CH 32                 // scan chunk length (timesteps per LDS stage)
#define LOGITS_OFF 0
#define VF_OFF   3932160
#define HT_OFF   4194304
#define CT_OFF   4325376

// y_sw swizzled layout: per 16-row tile rt: 1024 bf16 = [kf(2)][lane(64)][8],
// lane l holds rows m=l&15, k = 32*kf + 8*(l>>4) + j  (A-fragment order).

// ============================ encoder ============================
__global__ __launch_bounds__(256) void enc_kernel(
    const float* __restrict__ x, const float* __restrict__ W1, const float* __restrict__ b1,
    const float* __restrict__ W2, const float* __restrict__ b2, short* __restrict__ y_sw)
{
    __shared__ short w1t[64][136];       // [n][k]  (W1 transposed, bf16)
    __shared__ short w2t[64][72];
    __shared__ short c1buf[4][16][72];
    __shared__ short ybuf[4][16][72];

    const int tid  = threadIdx.x;
    const int lane = tid & 63;
    const int w    = tid >> 6;
    const int c    = lane & 15;
    const int q    = lane >> 4;

    for (int i = tid; i < 128*64; i += 256) { int k = i >> 6, n = i & 63; w1t[n][k] = f2bf(W1[i]); }
    for (int i = tid; i < 64*64;  i += 256) { int k = i >> 6, n = i & 63; w2t[n][k] = f2bf(W2[i]); }

    float b1v[4], b2v[4];
#pragma unroll
    for (int ct = 0; ct < 4; ++ct) { b1v[ct] = b1[16*ct + c]; b2v[ct] = b2[16*ct + c]; }
    __syncthreads();

    for (int it = 0; it < 4; ++it) {
        const int wt = it*4096 + blockIdx.x*4 + w;
        const int r0 = wt * 16;
        Frag af[4];
#pragma unroll
        for (int kf = 0; kf < 4; ++kf) {
            const float* xp = x + (size_t)(r0 + c)*FF + 32*kf + 8*q;
            f32x4 x0 = *(const f32x4*)xp;
            f32x4 x1 = *(const f32x4*)(xp + 4);
#pragma unroll
            for (int jj = 0; jj < 4; ++jj) { af[kf].s[jj] = f2bf(x0[jj]); af[kf].s[4+jj] = f2bf(x1[jj]); }
        }
        f32x4 acc[4];
#pragma unroll
        for (int ct = 0; ct < 4; ++ct) acc[ct] = (f32x4){b1v[ct], b1v[ct], b1v[ct], b1v[ct]};
#pragma unroll
        for (int kf = 0; kf < 4; ++kf)
#pragma unroll
            for (int ct = 0; ct < 4; ++ct) {
                Frag bf; bf.s = *(const s16x8*)&w1t[16*ct + c][32*kf + 8*q];
                acc[ct] = mfma16(af[kf].b, bf.b, acc[ct]);
            }
#pragma unroll
        for (int ct = 0; ct < 4; ++ct)
#pragma unroll
            for (int i = 0; i < 4; ++i)
                c1buf[w][4*q + i][16*ct + c] = f2bf(tanh_fast(acc[ct][i]));
        Frag a2[2];
#pragma unroll
        for (int kf = 0; kf < 2; ++kf) a2[kf].s = *(const s16x8*)&c1buf[w][c][32*kf + 8*q];
        f32x4 acc2[4];
#pragma unroll
        for (int ct = 0; ct < 4; ++ct) acc2[ct] = (f32x4){b2v[ct], b2v[ct], b2v[ct], b2v[ct]};
#pragma unroll
        for (int kf = 0; kf < 2; ++kf)
#pragma unroll
            for (int ct = 0; ct < 4; ++ct) {
                Frag bf; bf.s = *(const s16x8*)&w2t[16*ct + c][32*kf + 8*q];
                acc2[ct] = mfma16(a2[kf].b, bf.b, acc2[ct]);
            }
#pragma unroll
        for (int ct = 0; ct < 4; ++ct)
#pragma unroll
            for (int i = 0; i < 4; ++i)
                ybuf[w][4*q + i][16*ct + c] = f2bf(tanh_fast(acc2[ct][i]));
#pragma unroll
        for (int kf = 0; kf < 2; ++kf) {
            s16x8 yv = *(const s16x8*)&ybuf[w][c][32*kf + 8*q];
            *(s16x8*)(y_sw + (size_t)wt*1024 + kf*512 + lane*8) = yv;
        }
    }
}

// ============================ LSTM scan + fused heads ============================
// 128 blocks x 256 thr. Block owns 16 batch rows. Wave w owns hidden cols
// j in [16w,16w+16) for all 4 gates. y staged in CH-step LDS chunks via
// global_load_lds; heads computed in-loop (wave (t&3)), buffered in LDS,
// flushed at chunk boundaries => steady-state steps have ZERO outstanding
// vmcnt at __syncthreads (no per-step barrier drain).
__global__ __launch_bounds__(256, 1) void scan_kernel(
    const short* __restrict__ y_sw, const float* __restrict__ done,
    const float* __restrict__ h0, const float* __restrict__ c0,
    const float* __restrict__ Wih, const float* __restrict__ bih,
    const float* __restrict__ Whh, const float* __restrict__ bhh,
    const float* __restrict__ Wa, const float* __restrict__ ba,
    const float* __restrict__ Wc, const float* __restrict__ bc,
    float* __restrict__ out_logits, float* __restrict__ out_vf,
    float* __restrict__ hT_out, float* __restrict__ cT_out)
{
    __shared__ short ybuf[CH][1024];     // 64 KB  y chunk (A-frag order)
    __shared__ float obuf[CH][16][16];   // 32 KB  head outputs (15 logits + vf)
    __shared__ short hbuf[2][16][72];    // 4.6 KB double-buffered h (bf16)
    __shared__ float dbuf[TT][16];       // 8 KB   done for all steps

    const int tid  = threadIdx.x;
    const int lane = tid & 63;
    const int w    = tid >> 6;
    const int c    = lane & 15;
    const int q    = lane >> 4;
    const int blk  = blockIdx.x;
    const int b0   = blk * 16;
    const int jcol = 16*w + c;

    // ---- gate weight B-fragments (k<64: Wih, k>=64: Whh)
    Frag  wf[4][4];
    float biasv[4];
#pragma unroll
    for (int a = 0; a < 4; ++a) {
        const int col = 64*a + jcol;
        biasv[a] = bih[col] + bhh[col];
#pragma unroll
        for (int kf = 0; kf < 4; ++kf) {
            const float* wp = (kf < 2) ? (Wih + (size_t)col*HH + 32*kf + 8*q)
                                       : (Whh + (size_t)col*HH + 32*(kf-2) + 8*q);
            f32x4 w0 = *(const f32x4*)wp;
            f32x4 w1 = *(const f32x4*)(wp + 4);
#pragma unroll
            for (int jj = 0; jj < 4; ++jj) { wf[a][kf].s[jj] = f2bf(w0[jj]); wf[a][kf].s[4+jj] = f2bf(w1[jj]); }
        }
    }
    // ---- head B-fragments: col c (0..14 -> Wa, 15 -> Wc)
    Frag hwf[2]; float hbv;
#pragma unroll
    for (int kf = 0; kf < 2; ++kf)
#pragma unroll
        for (int jj = 0; jj < 8; ++jj) {
            int k = 32*kf + 8*q + jj;
            hwf[kf].s[jj] = f2bf((c < 15) ? Wa[k*AA + c] : Wc[k]);
        }
    hbv = (c < 15) ? ba[c] : bc[0];

    // ---- c state (fp32 regs): rows 4q+i, col jcol
    float cst[4];
#pragma unroll
    for (int i = 0; i < 4; ++i) cst[i] = c0[(size_t)(b0 + 4*q + i)*HH + jcol];
    // ---- h0 -> hbuf[0]
    {
        int mm = tid & 15, j4 = tid >> 4;
        f32x4 hv = *(const f32x4*)(h0 + (size_t)(b0 + mm)*HH + 4*j4);
#pragma unroll
        for (int ii = 0; ii < 4; ++ii) hbuf[0][mm][4*j4 + ii] = f2bf(hv[ii]);
    }
    // ---- done -> dbuf (global_load_lds, 8 insts across 4 waves)
#pragma unroll
    for (int i = 0; i < 2; ++i) {
        int j = w*2 + i;   // 0..7, covers steps 16j..16j+15
        const float* gp = done + (size_t)(16*j + (lane >> 2))*BB + b0 + 4*(lane & 3);
        GLDS(gp, &dbuf[16*j][0]);
    }
    // ---- y chunk 0 (64 insts across 4 waves)
#pragma unroll
    for (int i = 0; i < 16; ++i) {
        int idx = w*16 + i, ss = idx >> 1, hh = idx & 1;
        const short* gp = y_sw + ((size_t)ss*128 + blk)*1024 + hh*512 + lane*8;
        GLDS(gp, &ybuf[ss][hh*512]);
    }
    __builtin_amdgcn_s_waitcnt(0x0F70);   // vmcnt(0) only
    __syncthreads();

    for (int t = 0; t < TT; ++t) {
        const int cur = t & 1, nxt = cur ^ 1, s = t & (CH-1);
        // h_{t-1} A-fragments (also = z_{t-1} fragments, unmasked)
        Frag hf0, hf1;
        hf0.s = *(const s16x8*)&hbuf[cur][c][8*q];
        hf1.s = *(const s16x8*)&hbuf[cur][c][32 + 8*q];
        // fused head for z_{t-1}, one wave per step (rotating)
        if (t > 0 && ((t-1) & 3) == w) {
            f32x4 ha = (f32x4){hbv, hbv, hbv, hbv};
            ha = mfma16(hf0.b, hwf[0].b, ha);
            ha = mfma16(hf1.b, hwf[1].b, ha);
            const int slot = (t-1) & (CH-1);
#pragma unroll
            for (int i = 0; i < 4; ++i) obuf[slot][4*q + i][c] = ha[i];
        }
        // ---- chunk boundary: flush heads, stage next y chunk (one vm drain)
        if (s == 0 && t > 0) {
            __syncthreads();                       // obuf complete, ybuf free
#pragma unroll
            for (int i = 0; i < 16; ++i) {         // stage y[t .. t+CH)
                int idx = w*16 + i, ss = idx >> 1, hh = idx & 1;
                const short* gp = y_sw + ((size_t)(t + ss)*128 + blk)*1024 + hh*512 + lane*8;
                GLDS(gp, &ybuf[ss][hh*512]);
            }
#pragma unroll
            for (int rep = 0; rep < 2; ++rep) {    // flush steps t-CH..t-1
                int idx = rep*256 + tid, ss = idx >> 4, rr = idx & 15;
                size_t row = (size_t)(t - CH + ss)*BB + b0 + rr;
                const float* ob = &obuf[ss][rr][0];
                float* lp = out_logits + row*AA;
#pragma unroll
                for (int n = 0; n < 15; ++n) lp[n] = ob[n];
                out_vf[row] = ob[15];
            }
            __builtin_amdgcn_s_waitcnt(0x0F70);    // vmcnt(0) only
            __syncthreads();
        }
        // done-mask h (done is exactly 0.0 or 1.0)
        const float dmv = dbuf[t][c];
        const int msk = (dmv != 0.0f) ? 0 : -1;
        Frag h0m, h1m;
#pragma unroll
        for (int k = 0; k < 4; ++k) { h0m.i[k] = hf0.i[k] & msk; h1m.i[k] = hf1.i[k] & msk; }
        // y A-frags from LDS chunk
        Frag yc0, yc1;
        yc0.s = *(const s16x8*)&ybuf[s][lane*8];
        yc1.s = *(const s16x8*)&ybuf[s][512 + lane*8];
        // gates
        f32x4 acc[4];
#pragma unroll
        for (int a = 0; a < 4; ++a) {
            acc[a] = (f32x4){biasv[a], biasv[a], biasv[a], biasv[a]};
            acc[a] = mfma16(yc0.b, wf[a][0].b, acc[a]);
            acc[a] = mfma16(yc1.b, wf[a][1].b, acc[a]);
            acc[a] = mfma16(h0m.b, wf[a][2].b, acc[a]);
            acc[a] = mfma16(h1m.b, wf[a][3].b, acc[a]);
        }
        // elementwise LSTM cell (fp32 c state)
        const f32x4 dcv = *(const f32x4*)&dbuf[t][4*q];
#pragma unroll
        for (int i = 0; i < 4; ++i) {
            float gi = acc[0][i], gf = acc[1][i], gg = acc[2][i], go = acc[3][i];
            float cm = (dcv[i] != 0.0f) ? 0.0f : cst[i];
            float cn = sigm(gf)*cm + sigm(gi)*tanh_fast(gg);
            cst[i] = cn;
            hbuf[nxt][4*q + i][jcol] = f2bf(sigm(go)*tanh_fast(cn));
        }
        __syncthreads();   // steady state: lgkm drain only (no vm outstanding)
    }
    // ---- epilogue: head for z_127, flush last chunk, hT, cT
    {
        Frag hf0, hf1;
        hf0.s = *(const s16x8*)&hbuf[0][c][8*q];
        hf1.s = *(const s16x8*)&hbuf[0][c][32 + 8*q];
        if (((TT-1) & 3) == w) {
            f32x4 ha = (f32x4){hbv, hbv, hbv, hbv};
            ha = mfma16(hf0.b, hwf[0].b, ha);
            ha = mfma16(hf1.b, hwf[1].b, ha);
#pragma unroll
            for (int i = 0; i < 4; ++i) obuf[(TT-1) & (CH-1)][4*q + i][c] = ha[i];
        }
        __syncthreads();
#pragma unroll
        for (int rep = 0; rep < 2; ++rep) {
            int idx = rep*256 + tid, ss = idx >> 4, rr = idx & 15;
            size_t row = (size_t)(TT - CH + ss)*BB + b0 + rr;
            const float* ob = &obuf[ss][rr][0];
            float* lp = out_logits + row*AA;
#pragma unroll
            for (int n = 0; n < 15; ++n) lp[n] = ob[n];
            out_vf[row] = ob[15];
        }
        {
            int mm = tid & 15, j4 = tid >> 4;
            f32x4 hv;
#pragma unroll
            for (int ii = 0; ii < 4; ++ii) hv[ii] = bf2f(hbuf[0][mm][4*j4 + ii]);
            *(f32x4*)(hT_out + (size_t)(b0 + mm)*HH + 4*j4) = hv;
        }
#pragma unroll
        for (int i = 0; i < 4; ++i) cT_out[(size_t)(b0 + 4*q + i)*HH + jcol] = cst[i];
    }
}

// ============================ launch ============================
extern "C" void kernel_launch(void* const* d_in, const int* in_sizes, int n_in,
                              void* d_out, int out_size, void* d_ws, size_t ws_size,
                              hipStream_t stream) {
    const float* x    = (const float*)d_in[0];
    const float* done = (const float*)d_in[1];
    const float* h0   = (const float*)d_in[2];
    const float* c0   = (const float*)d_in[3];
    const float* W1   = (const float*)d_in[4];
    const float* b1   = (const float*)d_in[5];
    const float* W2   = (const float*)d_in[6];
    const float* b2   = (const float*)d_in[7];
    const float* Wih  = (const float*)d_in[8];
    const float* bih  = (const float*)d_in[9];
    const float* Whh  = (const float*)d_in[10];
    const float* bhh  = (const float*)d_in[11];
    const float* Wa   = (const float*)d_in[12];
    const float* ba   = (const float*)d_in[13];
    const float* Wc   = (const float*)d_in[14];
    const float* bc   = (const float*)d_in[15];
    float* out = (float*)d_out;

    short* y_sw = (short*)d_ws;     // 16,777,216 bf16 = 32 MiB

    enc_kernel<<<1024, 256, 0, stream>>>(x, W1, b1, W2, b2, y_sw);
    scan_kernel<<<128, 256, 0, stream>>>(y_sw, done, h0, c0, Wih, bih, Whh, bhh,
                                         Wa, ba, Wc, bc,
                                         out + LOGITS_OFF, out + VF_OFF,
                                         out + HT_OFF, out + CT_OFF);
}

// Round 3
// 319.560 us; speedup vs baseline: 1.0364x; 1.0349x over previous
//
#include <hip/hip_runtime.h>
#include <hip/hip_bf16.h>
#include <stdint.h>

// ---------- types ----------
typedef __bf16  bf16x8 __attribute__((ext_vector_type(8)));
typedef short   s16x8  __attribute__((ext_vector_type(8)));
typedef int     i32x4  __attribute__((ext_vector_type(4)));
typedef float   f32x4  __attribute__((ext_vector_type(4)));

union Frag { s16x8 s; bf16x8 b; i32x4 i; };

static __device__ __forceinline__ short f2bf(float f) {
    union { float f; unsigned u; } v; v.f = f;
    unsigned r = (v.u + 0x7FFFu + ((v.u >> 16) & 1u)) >> 16;   // RNE
    return (short)r;
}
static __device__ __forceinline__ float bf2f(short s) {
    union { unsigned u; float f; } v; v.u = ((unsigned)(unsigned short)s) << 16;
    return v.f;
}
static __device__ __forceinline__ float fast_rcp(float x) { return __builtin_amdgcn_rcpf(x); }
static __device__ __forceinline__ float sigm(float x) { return fast_rcp(1.0f + __expf(-x)); }
static __device__ __forceinline__ float tanh_fast(float x) {
    float e = __expf(-2.0f * x);
    return (1.0f - e) * fast_rcp(1.0f + e);
}
static __device__ __forceinline__ f32x4 mfma16(bf16x8 a, bf16x8 b, f32x4 c) {
    return __builtin_amdgcn_mfma_f32_16x16x32_bf16(a, b, c, 0, 0, 0);
}

#define GLDS(gp, lp) __builtin_amdgcn_global_load_lds( \
    (const __attribute__((address_space(1))) void*)(gp), \
    (__attribute__((address_space(3))) void*)(lp), 16, 0, 0)

// Constants
#define TT 128
#define BB 2048
#define HH 64
#define FF 128
#define AA 15
#define CH 8                  // y staging chunk (steps), double-buffered
#define LOGITS_OFF 0
#define VF_OFF   3932160
#define HT_OFF   4194304
#define CT_OFF   4325376

// y_sw swizzled: per 16-row tile: 1024 bf16 = [kf(2)][lane(64)][8] (A-frag order)

// ============================ encoder ============================
__global__ __launch_bounds__(256) void enc_kernel(
    const float* __restrict__ x, const float* __restrict__ W1, const float* __restrict__ b1,
    const float* __restrict__ W2, const float* __restrict__ b2, short* __restrict__ y_sw)
{
    __shared__ short w1t[64][136];
    __shared__ short w2t[64][72];
    __shared__ short c1buf[4][16][72];
    __shared__ short ybuf[4][16][72];

    const int tid  = threadIdx.x;
    const int lane = tid & 63;
    const int w    = tid >> 6;
    const int c    = lane & 15;
    const int q    = lane >> 4;

    for (int i = tid; i < 128*64; i += 256) { int k = i >> 6, n = i & 63; w1t[n][k] = f2bf(W1[i]); }
    for (int i = tid; i < 64*64;  i += 256) { int k = i >> 6, n = i & 63; w2t[n][k] = f2bf(W2[i]); }

    float b1v[4], b2v[4];
#pragma unroll
    for (int ct = 0; ct < 4; ++ct) { b1v[ct] = b1[16*ct + c]; b2v[ct] = b2[16*ct + c]; }
    __syncthreads();

    for (int it = 0; it < 4; ++it) {
        const int wt = it*4096 + blockIdx.x*4 + w;
        const int r0 = wt * 16;
        Frag af[4];
#pragma unroll
        for (int kf = 0; kf < 4; ++kf) {
            const float* xp = x + (size_t)(r0 + c)*FF + 32*kf + 8*q;
            f32x4 x0 = *(const f32x4*)xp;
            f32x4 x1 = *(const f32x4*)(xp + 4);
#pragma unroll
            for (int jj = 0; jj < 4; ++jj) { af[kf].s[jj] = f2bf(x0[jj]); af[kf].s[4+jj] = f2bf(x1[jj]); }
        }
        f32x4 acc[4];
#pragma unroll
        for (int ct = 0; ct < 4; ++ct) acc[ct] = (f32x4){b1v[ct], b1v[ct], b1v[ct], b1v[ct]};
#pragma unroll
        for (int kf = 0; kf < 4; ++kf)
#pragma unroll
            for (int ct = 0; ct < 4; ++ct) {
                Frag bf; bf.s = *(const s16x8*)&w1t[16*ct + c][32*kf + 8*q];
                acc[ct] = mfma16(af[kf].b, bf.b, acc[ct]);
            }
#pragma unroll
        for (int ct = 0; ct < 4; ++ct)
#pragma unroll
            for (int i = 0; i < 4; ++i)
                c1buf[w][4*q + i][16*ct + c] = f2bf(tanh_fast(acc[ct][i]));
        Frag a2[2];
#pragma unroll
        for (int kf = 0; kf < 2; ++kf) a2[kf].s = *(const s16x8*)&c1buf[w][c][32*kf + 8*q];
        f32x4 acc2[4];
#pragma unroll
        for (int ct = 0; ct < 4; ++ct) acc2[ct] = (f32x4){b2v[ct], b2v[ct], b2v[ct], b2v[ct]};
#pragma unroll
        for (int kf = 0; kf < 2; ++kf)
#pragma unroll
            for (int ct = 0; ct < 4; ++ct) {
                Frag bf; bf.s = *(const s16x8*)&w2t[16*ct + c][32*kf + 8*q];
                acc2[ct] = mfma16(a2[kf].b, bf.b, acc2[ct]);
            }
#pragma unroll
        for (int ct = 0; ct < 4; ++ct)
#pragma unroll
            for (int i = 0; i < 4; ++i)
                ybuf[w][4*q + i][16*ct + c] = f2bf(tanh_fast(acc2[ct][i]));
#pragma unroll
        for (int kf = 0; kf < 2; ++kf) {
            s16x8 yv = *(const s16x8*)&ybuf[w][c][32*kf + 8*q];
            *(s16x8*)(y_sw + (size_t)wt*1024 + kf*512 + lane*8) = yv;
        }
    }
}

// ============================ LSTM scan (specialized waves) ============================
// 128 blocks x 512 thr. Waves 0-3: critical path (h@Whh MFMA + elementwise,
// write-side done-masking). Waves 4-7: helpers (gy[t+1]=bias+y@Wih precompute,
// y chunk staging via global_load_lds, heads for z[t-1], output flush).
__global__ __launch_bounds__(512, 1) void scan_kernel(
    const short* __restrict__ y_sw, const float* __restrict__ done,
    const float* __restrict__ h0, const float* __restrict__ c0,
    const float* __restrict__ Wih, const float* __restrict__ bih,
    const float* __restrict__ Whh, const float* __restrict__ bhh,
    const float* __restrict__ Wa, const float* __restrict__ ba,
    const float* __restrict__ Wc, const float* __restrict__ bc,
    float* __restrict__ out_logits, float* __restrict__ out_vf,
    float* __restrict__ hT_out, float* __restrict__ cT_out)
{
    __shared__ short ybuf[2][CH][1024];     // 32 KB  staged y (A-frag order), dbl-buf
    __shared__ float gybuf[2][4][4][256];   // 32 KB  gy = bias + y@Wih^T, dbl-buf
    __shared__ float obuf[2][CH][16][16];   // 16 KB  head outputs, dbl-buf by chunk
    __shared__ short zbuf[2][16][72];       // 4.6 KB unmasked h (for heads/hT)
    __shared__ short hbuf[2][16][72];       // 4.6 KB masked h (scan state)
    __shared__ float dbuf[TT+1][16];        // 8.3 KB done, +zero row 128

    const int tid  = threadIdx.x;
    const int lane = tid & 63;
    const int w    = tid >> 6;
    const int c    = lane & 15;
    const int q    = lane >> 4;
    const int blk  = blockIdx.x;
    const int b0   = blk * 16;
    const bool crit = (w < 4);
    const int hw   = w - 4;

    // ---------------- per-role register state ----------------
    Frag  wf[4][2];      // crit: Whh B-frags        helper: Wih B-frags
    float biasv[4];      // helper only
    Frag  hwf[2];        // helper: head B-frags
    float hbv = 0.f;     // helper: head bias
    float cst[4];        // crit: c state

    if (crit) {
        const int jcol = 16*w + c;
#pragma unroll
        for (int a = 0; a < 4; ++a) {
            const int col = 64*a + jcol;
#pragma unroll
            for (int kf = 0; kf < 2; ++kf) {
                const float* wp = Whh + (size_t)col*HH + 32*kf + 8*q;
                f32x4 w0 = *(const f32x4*)wp;
                f32x4 w1 = *(const f32x4*)(wp + 4);
#pragma unroll
                for (int jj = 0; jj < 4; ++jj) { wf[a][kf].s[jj] = f2bf(w0[jj]); wf[a][kf].s[4+jj] = f2bf(w1[jj]); }
            }
        }
    } else {
        const int jcolh = 16*hw + c;
#pragma unroll
        for (int a = 0; a < 4; ++a) {
            const int col = 64*a + jcolh;
            biasv[a] = bih[col] + bhh[col];
#pragma unroll
            for (int kf = 0; kf < 2; ++kf) {
                const float* wp = Wih + (size_t)col*HH + 32*kf + 8*q;
                f32x4 w0 = *(const f32x4*)wp;
                f32x4 w1 = *(const f32x4*)(wp + 4);
#pragma unroll
                for (int jj = 0; jj < 4; ++jj) { wf[a][kf].s[jj] = f2bf(w0[jj]); wf[a][kf].s[4+jj] = f2bf(w1[jj]); }
            }
        }
#pragma unroll
        for (int kf = 0; kf < 2; ++kf)
#pragma unroll
            for (int jj = 0; jj < 8; ++jj) {
                int k = 32*kf + 8*q + jj;
                hwf[kf].s[jj] = f2bf((c < 15) ? Wa[k*AA + c] : Wc[k]);
            }
        hbv = (c < 15) ? ba[c] : bc[0];
        // ---- stage done (all 128 steps) + y chunk 0
#pragma unroll
        for (int i = 0; i < 2; ++i) {
            int j = hw*2 + i;   // 0..7 -> steps 16j..16j+15
            const float* gp = done + (size_t)(16*j + (lane >> 2))*BB + b0 + 4*(lane & 3);
            GLDS(gp, &dbuf[16*j][0]);
        }
#pragma unroll
        for (int i = 0; i < 4; ++i) {
            int idx = hw*4 + i, ss = idx >> 1, half = idx & 1;
            const short* gp = y_sw + ((size_t)ss*128 + blk)*1024 + half*512 + lane*8;
            GLDS(gp, &ybuf[0][ss][half*512]);
        }
        __builtin_amdgcn_s_waitcnt(0x0F70);   // vmcnt(0)
    }
    if (tid < 16) dbuf[TT][tid] = 0.0f;       // mask row for t=127 write-side
    __syncthreads();   // A: dbuf + ybuf[0] visible

    if (crit) {
        const int jcol = 16*w + c;
        // c state init (masked by done[0])
#pragma unroll
        for (int i = 0; i < 4; ++i) {
            float d0 = dbuf[0][4*q + i];
            float cv = c0[(size_t)(b0 + 4*q + i)*HH + jcol];
            cst[i] = (d0 != 0.0f) ? 0.0f : cv;
        }
        // h0 (masked) -> hbuf[0]
        int mm = tid & 15, j4 = (tid >> 4) & 15;
        float dm = dbuf[0][mm];
        f32x4 hv = *(const f32x4*)(h0 + (size_t)(b0 + mm)*HH + 4*j4);
#pragma unroll
        for (int ii = 0; ii < 4; ++ii)
            hbuf[0][mm][4*j4 + ii] = (dm != 0.0f) ? (short)0 : f2bf(hv[ii]);
    } else {
        // gy[0] = bias + y0@Wih^T
        Frag yc0, yc1;
        yc0.s = *(const s16x8*)&ybuf[0][0][lane*8];
        yc1.s = *(const s16x8*)&ybuf[0][0][512 + lane*8];
#pragma unroll
        for (int a = 0; a < 4; ++a) {
            f32x4 g = (f32x4){biasv[a], biasv[a], biasv[a], biasv[a]};
            g = mfma16(yc0.b, wf[0+a][0].b, g);   // (indexing kept explicit below)
            g = mfma16(yc1.b, wf[a][1].b, g);
            // note: first mfma line uses wf[a][0]; written this way to avoid
            // any accidental aliasing — recompute properly:
            f32x4 gg = (f32x4){biasv[a], biasv[a], biasv[a], biasv[a]};
            gg = mfma16(yc0.b, wf[a][0].b, gg);
            gg = mfma16(yc1.b, wf[a][1].b, gg);
            *(f32x4*)&gybuf[0][hw][a][lane*4] = gg;
        }
    }
    __syncthreads();   // B: gybuf[0] + hbuf[0] ready

    for (int t = 0; t < TT; ++t) {
        if (crit) {
            const int jcol = 16*w + c;
            const int cur = t & 1;
            // ---- critical chain: h frags + gy -> 8 MFMA -> elementwise
            Frag hf0, hf1;
            hf0.s = *(const s16x8*)&hbuf[cur][c][8*q];
            hf1.s = *(const s16x8*)&hbuf[cur][c][32 + 8*q];
            f32x4 acc[4];
#pragma unroll
            for (int a = 0; a < 4; ++a) acc[a] = *(const f32x4*)&gybuf[cur][w][a][lane*4];
#pragma unroll
            for (int a = 0; a < 4; ++a) {
                acc[a] = mfma16(hf0.b, wf[a][0].b, acc[a]);
                acc[a] = mfma16(hf1.b, wf[a][1].b, acc[a]);
            }
            const f32x4 dn = *(const f32x4*)&dbuf[t+1][4*q];   // mask for NEXT step
#pragma unroll
            for (int i = 0; i < 4; ++i) {
                float gi = acc[0][i], gf = acc[1][i], gg = acc[2][i], go = acc[3][i];
                float cn = sigm(gf)*cst[i] + sigm(gi)*tanh_fast(gg);
                float h  = sigm(go)*tanh_fast(cn);
                short zb = f2bf(h);
                zbuf[cur][4*q + i][jcol] = zb;                  // unmasked (output)
                const bool d = (dn[i] != 0.0f);
                cst[i] = d ? 0.0f : cn;                         // write-side mask
                hbuf[cur ^ 1][4*q + i][jcol] = d ? (short)0 : zb;
            }
        } else {
            // ---- helpers: staging / flush / head / gy[t+1]
            if ((t & 7) == 0 && t < 120) {        // stage y chunk (t/8)+1
                const int k = (t >> 3) + 1;
#pragma unroll
                for (int i = 0; i < 4; ++i) {
                    int idx = hw*4 + i, ss = idx >> 1, half = idx & 1;
                    const short* gp = y_sw + ((size_t)(8*k + ss)*128 + blk)*1024 + half*512 + lane*8;
                    GLDS(gp, &ybuf[k & 1][ss][half*512]);
                }
            }
            if ((t & 7) == 1 && t > 8 && w < 6) { // flush chunk (t/8)-1 outputs
                const int cc = (t >> 3) - 1;
                const int idx = (w - 4)*64 + lane;   // 0..127
                const int s = idx >> 4, r = idx & 15;
                const size_t row = (size_t)(8*cc + s)*BB + b0 + r;
                const float* ob = &obuf[cc & 1][s][r][0];
                float* lp = out_logits + row*AA;
#pragma unroll
                for (int n = 0; n < 15; ++n) lp[n] = ob[n];
                out_vf[row] = ob[15];
            }
            if (t >= 1 && w == 4 + ((t-1) & 3)) { // head for z[t-1]
                const int tp = t - 1;
                Frag zf0, zf1;
                zf0.s = *(const s16x8*)&zbuf[tp & 1][c][8*q];
                zf1.s = *(const s16x8*)&zbuf[tp & 1][c][32 + 8*q];
                f32x4 ha = (f32x4){hbv, hbv, hbv, hbv};
                ha = mfma16(zf0.b, hwf[0].b, ha);
                ha = mfma16(zf1.b, hwf[1].b, ha);
#pragma unroll
                for (int i = 0; i < 4; ++i)
                    obuf[(tp >> 3) & 1][tp & 7][4*q + i][c] = ha[i];
            }
            if (t < TT-1) {                        // gy[t+1]
                const int tn = t + 1;
                const int ch = (tn >> 3) & 1, sl = tn & 7;
                Frag yc0, yc1;
                yc0.s = *(const s16x8*)&ybuf[ch][sl][lane*8];
                yc1.s = *(const s16x8*)&ybuf[ch][sl][512 + lane*8];
#pragma unroll
                for (int a = 0; a < 4; ++a) {
                    f32x4 g = (f32x4){biasv[a], biasv[a], biasv[a], biasv[a]};
                    g = mfma16(yc0.b, wf[a][0].b, g);
                    g = mfma16(yc1.b, wf[a][1].b, g);
                    *(f32x4*)&gybuf[tn & 1][hw][a][lane*4] = g;
                }
            }
            if ((t & 7) == 6)                      // drain staging off crit path
                __builtin_amdgcn_s_waitcnt(0x0F70);
        }
        __syncthreads();
    }

    // ---------------- epilogue ----------------
    if (!crit && w == 7) {                         // head for z[127]
        Frag zf0, zf1;
        zf0.s = *(const s16x8*)&zbuf[1][c][8*q];
        zf1.s = *(const s16x8*)&zbuf[1][c][32 + 8*q];
        f32x4 ha = (f32x4){hbv, hbv, hbv, hbv};
        ha = mfma16(zf0.b, hwf[0].b, ha);
        ha = mfma16(zf1.b, hwf[1].b, ha);
#pragma unroll
        for (int i = 0; i < 4; ++i) obuf[1][7][4*q + i][c] = ha[i];
    }
    __syncthreads();
    if (!crit && w < 6) {                          // flush chunk 15
        const int idx = (w - 4)*64 + lane;
        const int s = idx >> 4, r = idx & 15;
        const size_t row = (size_t)(120 + s)*BB + b0 + r;
        const float* ob = &obuf[1][s][r][0];
        float* lp = out_logits + row*AA;
#pragma unroll
        for (int n = 0; n < 15; ++n) lp[n] = ob[n];
        out_vf[row] = ob[15];
    }
    if (crit) {
        const int jcol = 16*w + c;
        int mm = tid & 15, j4 = (tid >> 4) & 15;
        f32x4 hv;
#pragma unroll
        for (int ii = 0; ii < 4; ++ii) hv[ii] = bf2f(zbuf[1][mm][4*j4 + ii]);  // z127 = hT
        *(f32x4*)(hT_out + (size_t)(b0 + mm)*HH + 4*j4) = hv;
#pragma unroll
        for (int i = 0; i < 4; ++i) cT_out[(size_t)(b0 + 4*q + i)*HH + jcol] = cst[i];
    }
}

// ============================ launch ============================
extern "C" void kernel_launch(void* const* d_in, const int* in_sizes, int n_in,
                              void* d_out, int out_size, void* d_ws, size_t ws_size,
                              hipStream_t stream) {
    const float* x    = (const float*)d_in[0];
    const float* done = (const float*)d_in[1];
    const float* h0   = (const float*)d_in[2];
    const float* c0   = (const float*)d_in[3];
    const float* W1   = (const float*)d_in[4];
    const float* b1   = (const float*)d_in[5];
    const float* W2   = (const float*)d_in[6];
    const float* b2   = (const float*)d_in[7];
    const float* Wih  = (const float*)d_in[8];
    const float* bih  = (const float*)d_in[9];
    const float* Whh  = (const float*)d_in[10];
    const float* bhh  = (const float*)d_in[11];
    const float* Wa   = (const float*)d_in[12];
    const float* ba   = (const float*)d_in[13];
    const float* Wc   = (const float*)d_in[14];
    const float* bc   = (const float*)d_in[15];
    float* out = (float*)d_out;

    short* y_sw = (short*)d_ws;     // 32 MiB swizzled encoder output

    enc_kernel<<<1024, 256, 0, stream>>>(x, W1, b1, W2, b2, y_sw);
    scan_kernel<<<128, 512, 0, stream>>>(y_sw, done, h0, c0, Wih, bih, Whh, bhh,
                                         Wa, ba, Wc, bc,
                                         out + LOGITS_OFF, out + VF_OFF,
                                         out + HT_OFF, out + CT_OFF);
}